// Round 11
// baseline (308.062 us; speedup 1.0000x reference)
//
#include <hip/hip_runtime.h>
#include <hip/hip_bf16.h>
#include <cstdint>

// Quantized int8 3x3 conv, N=32 Cin=256 H=W=56 Cout=256 -> out int32 [32,256,54,54]
// NOTE: harness uploads ALL integer inputs as int32 ("integer -> const int*"),
// so inputVec/weight/zeropoints are int32 buffers holding int8-range values.
//
// conv = c1[co]*S1 + c2[co]*S3[m] + c3[co]
//   c1 = 0.01*scale, c2 = -zp*c1, c3 = bias + 7*c1*(zp*2304 - S2)
// S1 via int8 implicit GEMM (MFMA i32_16x16x64_i8), S2/S3 precomputed.

using i32x4 = __attribute__((ext_vector_type(4))) int;

#define NB    32
#define CIN   256
#define HIN   56
#define WIN   56
#define COUT  256
#define HOUT  54
#define WOUT  54
#define MTOT  (NB*HOUT*WOUT)       // 93312
#define HWOUT (HOUT*WOUT)          // 2916
#define PIX   (NB*HIN*WIN)         // 100352

// workspace layout (bytes)
#define OFF_NHWC 0u
#define SZ_NHWC  (PIX*256)                 // 25690112
#define OFF_WT   (OFF_NHWC + SZ_NHWC)      // wT[9][256][256] co-major rows
#define SZ_WT    (9*256*256)               // 589824
#define OFF_CS   (OFF_WT + SZ_WT)          // colsum [PIX] int
#define SZ_CS    (PIX*4)
#define OFF_S3   (OFF_CS + SZ_CS)          // S3 [MTOT] int
#define SZ_S3    (MTOT*4)
#define OFF_C1   (OFF_S3 + SZ_S3)
#define OFF_C2   (OFF_C1 + 1024)
#define OFF_C3   (OFF_C2 + 1024)

__device__ inline int bytesum4(int v) {
    return (int)(int8_t)(v) + (int)(int8_t)(v >> 8) +
           (int)(int8_t)(v >> 16) + (int)(int8_t)(v >> 24);
}

// ---------------- K1: NCHW int32 -> NHWC int8 ----------------
// block = (n, h); 256 threads = 4 waves. Wave wq covers w = wq*14..+13;
// lane covers ci = 4*lane..+3. Pack 4 ci bytes/word into LDS [w][ci4]
// (padded, conflict-free), then write nhwc with coalesced 16B chunks.
__global__ __launch_bounds__(256) void k_transpose(const int* __restrict__ in,
                                                   int8_t* __restrict__ nhwc) {
    __shared__ uint32_t ldsw[56][68];    // [w][ci4], 68-word pitch (16B-aligned rows)
    const int b = blockIdx.x;            // 32*56
    const int n = b / 56, h = b % 56;
    const int t = threadIdx.x;
    const int wq = t >> 6, lane = t & 63;
    int v[4][14];
#pragma unroll
    for (int j = 0; j < 4; ++j) {
        const int* src = in + ((size_t)(n * 256 + lane * 4 + j) * 56 + h) * 56 + wq * 14;
#pragma unroll
        for (int i = 0; i < 14; ++i) v[j][i] = src[i];
    }
#pragma unroll
    for (int i = 0; i < 14; ++i) {
        uint32_t d = ((uint32_t)(v[0][i] & 0xff)) |
                     ((uint32_t)(v[1][i] & 0xff) << 8) |
                     ((uint32_t)(v[2][i] & 0xff) << 16) |
                     ((uint32_t)(v[3][i] & 0xff) << 24);
        ldsw[wq * 14 + i][lane] = d;
    }
    __syncthreads();
    // 56 pixels * 16 chunks of 16B = 896 chunks
    int8_t* dst = nhwc + (size_t)((n * 56 + h) * 56) * 256;
#pragma unroll
    for (int j = 0; j < 4; ++j) {
        const int c = t + j * 256;
        if (c < 896) {
            const int w = c >> 4, c16 = c & 15;
            *(int4*)(dst + (size_t)w * 256 + c16 * 16) =
                *(const int4*)&ldsw[w][c16 * 4];
        }
    }
}

// ---------------- K2: per-pixel channel sum (reads int8 nhwc) ----------------
__global__ __launch_bounds__(256) void k_colsum(const int8_t* __restrict__ nhwc,
                                                int* __restrict__ colsum) {
    const int pix = blockIdx.x * 256 + threadIdx.x;   // 392*256 == PIX exactly
    const int* p = (const int*)(nhwc + (size_t)pix * 256);
    int s = 0;
#pragma unroll
    for (int q = 0; q < 64; ++q) s += bytesum4(p[q]);
    colsum[pix] = s;
}

// ---------------- K3: 3x3 box sum -> S3 ----------------
__global__ __launch_bounds__(256) void k_box(const int* __restrict__ colsum,
                                             int* __restrict__ S3) {
    const int m = blockIdx.x * 256 + threadIdx.x;
    if (m >= MTOT) return;
    const int n = m / HWOUT, rem = m - n * HWOUT;
    const int oh = rem / WOUT, ow = rem - oh * WOUT;
    const int* base = colsum + (n * 56 + oh) * 56 + ow;
    int s = 0;
#pragma unroll
    for (int r = 0; r < 3; ++r) s += base[r * 56] + base[r * 56 + 1] + base[r * 56 + 2];
    S3[m] = s;
}

// ---------------- K4: weight int32 OIHW -> int8 wT[rs][co][ci] ----------------
__global__ __launch_bounds__(256) void k_wpack(const int* __restrict__ wgt,
                                               int8_t* __restrict__ wT) {
    const int tid = blockIdx.x * 256 + threadIdx.x;   // 65536
    const int co = tid >> 8, ci = tid & 255;
    const int* src = wgt + (size_t)(co * 256 + ci) * 9;
#pragma unroll
    for (int rs = 0; rs < 9; ++rs)
        wT[(size_t)rs * 65536 + co * 256 + ci] = (int8_t)src[rs];
}

// ---------------- K5: per-co constants (int32 weights) ----------------
__global__ __launch_bounds__(64) void k_consts(const int* __restrict__ wgt,
                                               const float* __restrict__ scales,
                                               const int* __restrict__ zps,
                                               const float* __restrict__ bias,
                                               float* __restrict__ C1,
                                               float* __restrict__ C2,
                                               float* __restrict__ C3) {
    __shared__ int part[64];
    const int co = blockIdx.x, t = threadIdx.x;
    const int* p = wgt + (size_t)co * 2304;
    int s = 0;
#pragma unroll
    for (int q = 0; q < 36; ++q) s += p[t * 36 + q];
    part[t] = s;
    __syncthreads();
    if (t == 0) {
        int tot = 0;
#pragma unroll
        for (int i = 0; i < 64; ++i) tot += part[i];
        const float c1 = scales[co] * 0.01f;
        const float zp = (float)zps[co];
        C1[co] = c1;
        C2[co] = -zp * c1;
        C3[co] = bias[co] + c1 * 7.0f * (zp * 2304.0f - (float)tot);
    }
}

// ---------------- K6: implicit GEMM, int8 MFMA ----------------
// M = 93312 pixels (BM=128), N = 256 co (BN=128), K = 9 rs * 256 ci (BK=64B steps, 36 total)
// 256 threads = 4 waves (2x2), wave tile 64x64, mfma_i32_16x16x64_i8 4x4 frags.
__global__ __launch_bounds__(256, 2) void k_gemm(const int8_t* __restrict__ nhwc,
                                                 const int8_t* __restrict__ wT,
                                                 const int* __restrict__ S3,
                                                 const float* __restrict__ C1,
                                                 const float* __restrict__ C2,
                                                 const float* __restrict__ C3,
                                                 int* __restrict__ out) {
    __shared__ int8_t lds[2][16384];   // per buf: A [128][64] @0, B [128][64] @8192

    const int t = threadIdx.x;
    const int lane = t & 63, wv = t >> 6;
    const int m0 = blockIdx.x * 128;
    const int co0 = blockIdx.y * 128;

    // staging global offsets (pre-swizzled source; LDS dest stays linear: rule #21)
    size_t gA[2], gB[2];
#pragma unroll
    for (int L = 0; L < 2; ++L) {
        const int p = L * 64 + wv * 16 + (lane >> 2);      // tile row this lane fills
        const int seg = (lane & 3) ^ (p & 3);              // XOR slot swizzle
        const int m = m0 + p;
        const int n = m / HWOUT;
        const int rem = m - n * HWOUT;
        const int oh = rem / WOUT, ow = rem - oh * WOUT;
        gA[L] = (size_t)((n * 56 + oh) * 56 + ow) * 256 + seg * 16;
        gB[L] = (size_t)(co0 + p) * 256 + seg * 16;
    }

    i32x4 acc[4][4];
#pragma unroll
    for (int mi = 0; mi < 4; ++mi)
#pragma unroll
        for (int nj = 0; nj < 4; ++nj) acc[mi][nj] = (i32x4){0, 0, 0, 0};

    const int wm = wv >> 1, wn = wv & 1;
    const int r15 = lane & 15, kg = lane >> 4;
    const int slot = ((kg ^ (lane & 3)) & 3) * 16;         // read-side inverse swizzle
    int rA[4], rB[4];
#pragma unroll
    for (int i = 0; i < 4; ++i) {
        rA[i] = (wm * 64 + i * 16 + r15) * 64 + slot;
        rB[i] = 8192 + (wn * 64 + i * 16 + r15) * 64 + slot;
    }

    auto stage = [&](int step, int buf) {
        const int rs = step >> 2, kk = step & 3;
        const int r = rs / 3, s = rs - r * 3;
        const size_t aoff = (size_t)((r * 56 + s) * 256 + kk * 64);
        const size_t boff = (size_t)(rs * 65536 + kk * 64);
        int8_t* lb = lds[buf];
#pragma unroll
        for (int L = 0; L < 2; ++L) {
            __builtin_amdgcn_global_load_lds(
                (const __attribute__((address_space(1))) void*)(nhwc + gA[L] + aoff),
                (__attribute__((address_space(3))) void*)(lb + L * 4096 + wv * 1024),
                16, 0, 0);
            __builtin_amdgcn_global_load_lds(
                (const __attribute__((address_space(1))) void*)(wT + gB[L] + boff),
                (__attribute__((address_space(3))) void*)(lb + 8192 + L * 4096 + wv * 1024),
                16, 0, 0);
        }
    };

    stage(0, 0);
    __syncthreads();
    int cur = 0;
    for (int step = 0; step < 36; ++step) {
        if (step + 1 < 36) stage(step + 1, cur ^ 1);
        i32x4 av[4], bv[4];
#pragma unroll
        for (int i = 0; i < 4; ++i) av[i] = *(const i32x4*)(lds[cur] + rA[i]);
#pragma unroll
        for (int i = 0; i < 4; ++i) bv[i] = *(const i32x4*)(lds[cur] + rB[i]);
#pragma unroll
        for (int mi = 0; mi < 4; ++mi)
#pragma unroll
            for (int nj = 0; nj < 4; ++nj)
                acc[mi][nj] = __builtin_amdgcn_mfma_i32_16x16x64_i8(av[mi], bv[nj],
                                                                    acc[mi][nj], 0, 0, 0);
        __syncthreads();
        cur ^= 1;
    }

    // epilogue: out[n][co][oh][ow], C frag: col(co)=lane&15, row(m)=(lane>>4)*4+e
    float c1v[4], c2v[4], c3v[4];
    int cog[4];
#pragma unroll
    for (int nj = 0; nj < 4; ++nj) {
        const int co = co0 + wn * 64 + nj * 16 + r15;
        cog[nj] = co;
        c1v[nj] = C1[co];
        c2v[nj] = C2[co];
        c3v[nj] = C3[co];
    }
#pragma unroll
    for (int mi = 0; mi < 4; ++mi) {
        const int mb = m0 + wm * 64 + mi * 16 + kg * 4;    // 4 consecutive m, 16B aligned
        const int4 s3 = *(const int4*)(S3 + mb);
        const int n = mb / HWOUT;
        const int hw = mb - n * HWOUT;                     // 4-group never crosses n (2916%4==0)
#pragma unroll
        for (int nj = 0; nj < 4; ++nj) {
            int4 o;
#pragma unroll
            for (int e = 0; e < 4; ++e) {
                const float s1 = (float)acc[mi][nj][e];
                const float s3f = (float)((&s3.x)[e]);
                float v = fmaf(c1v[nj], s1, fmaf(c2v[nj], s3f, c3v[nj]));
                float rr = rintf(v);                       // RTE == jnp.round
                rr = fminf(fmaxf(rr, -2147483648.0f), 2147483520.0f);
                (&o.x)[e] = (int)rr;
            }
            *(int4*)(out + (size_t)(n * 256 + cog[nj]) * HWOUT + hw) = o;
        }
    }
}

extern "C" void kernel_launch(void* const* d_in, const int* in_sizes, int n_in,
                              void* d_out, int out_size, void* d_ws, size_t ws_size,
                              hipStream_t stream) {
    const int* inp      = (const int*)d_in[0];     // int32-widened int8
    const int* wgt      = (const int*)d_in[1];     // int32-widened int8
    const float* scales = (const float*)d_in[2];
    const int* zps      = (const int*)d_in[3];
    const float* bias   = (const float*)d_in[4];
    int* out            = (int*)d_out;

    uint8_t* ws = (uint8_t*)d_ws;
    int8_t* nhwc = (int8_t*)(ws + OFF_NHWC);
    int8_t* wT   = (int8_t*)(ws + OFF_WT);
    int* colsum  = (int*)(ws + OFF_CS);
    int* S3      = (int*)(ws + OFF_S3);
    float* C1    = (float*)(ws + OFF_C1);
    float* C2    = (float*)(ws + OFF_C2);
    float* C3    = (float*)(ws + OFF_C3);

    k_transpose<<<32 * 56, 256, 0, stream>>>(inp, nhwc);
    k_colsum<<<PIX / 256, 256, 0, stream>>>(nhwc, colsum);
    k_box<<<(MTOT + 255) / 256, 256, 0, stream>>>(colsum, S3);
    k_wpack<<<65536 / 256, 256, 0, stream>>>(wgt, wT);
    k_consts<<<256, 64, 0, stream>>>(wgt, scales, zps, bias, C1, C2, C3);

    dim3 grid(MTOT / 128, COUT / 128);
    k_gemm<<<grid, 256, 0, stream>>>(nhwc, wT, S3, C1, C2, C3, out);
}